// Round 2
// baseline (129.166 us; speedup 1.0000x reference)
//
#include <hip/hip_runtime.h>

#define BATCH 262144
#define HID 64
#define NSTEP 50

// One thread per batch element, t-outer / h-inner.
// Per-h state (m, carried spike, loop-invariant cur1) lives in fully-unrolled
// statically-indexed registers; per-t layer-2 accumulators are 2 scalars, so
// nothing is runtime-indexed -> no scratch (round-1 had VGPR=56 => acc[50]
// array spilled to local memory).
// Arithmetic order identical to the passing round-1 kernel:
//   m = rn(rn(rn(0.95*m) + cur) - spk); spk = (m>1) ? 1 : 0
//   cur2 accumulated over h=0..63 by sequential fma; +b2 as separate add.
__global__ __launch_bounds__(256, 2) void snn_fused(
    const float* __restrict__ x,
    const float* __restrict__ W1,
    const float* __restrict__ b1,
    const float* __restrict__ W2,
    const float* __restrict__ b2,
    float* __restrict__ out)
{
    const int b = blockIdx.x * 256 + threadIdx.x;
    const float2 xv = reinterpret_cast<const float2*>(x)[b];

    float cur[HID], m[HID], spk[HID];
#pragma unroll
    for (int h = 0; h < HID; ++h) {
        // cur1_h = rn(rn(fma(x1,w11, rn(x0*w10))) + b1[h])  (same as round 1)
        float c = __fmul_rn(xv.x, W1[2 * h + 0]);
        c = __builtin_fmaf(xv.y, W1[2 * h + 1], c);
        cur[h] = __fadd_rn(c, b1[h]);
        m[h] = 0.0f;
        spk[h] = 0.0f;
    }

    const float bb0 = b2[0], bb1 = b2[1];
    float m0 = 0.0f, m1 = 0.0f, s0 = 0.0f, s1 = 0.0f;
    float2* outspk = reinterpret_cast<float2*>(out) + b;                         // [t][b][2]
    float2* outmem = reinterpret_cast<float2*>(out) + (size_t)NSTEP * BATCH + b;

#pragma unroll 1
    for (int t = 0; t < NSTEP; ++t) {
        float a0 = 0.0f, a1 = 0.0f;
#pragma unroll
        for (int h = 0; h < HID; ++h) {
            // LIF layer 1, exact rounded-op order; spk[h] is spike(t-1) == reset(t)
            m[h] = __fsub_rn(__fadd_rn(__fmul_rn(0.95f, m[h]), cur[h]), spk[h]);
            spk[h] = (m[h] > 1.0f) ? 1.0f : 0.0f;
            // cur2 partial sums, sequential-h fma order (matches round 1)
            a0 = __builtin_fmaf(spk[h], W2[h], a0);        // W2[0][h]
            a1 = __builtin_fmaf(spk[h], W2[HID + h], a1);  // W2[1][h]
        }
        // LIF layer 2 + coalesced interleaved stores
        const float c0 = __fadd_rn(a0, bb0);
        const float c1 = __fadd_rn(a1, bb1);
        m0 = __fsub_rn(__fadd_rn(__fmul_rn(0.95f, m0), c0), s0);
        m1 = __fsub_rn(__fadd_rn(__fmul_rn(0.95f, m1), c1), s1);
        s0 = (m0 > 1.0f) ? 1.0f : 0.0f;
        s1 = (m1 > 1.0f) ? 1.0f : 0.0f;
        outspk[(size_t)t * BATCH] = make_float2(s0, s1);
        outmem[(size_t)t * BATCH] = make_float2(m0, m1);
    }
}

extern "C" void kernel_launch(void* const* d_in, const int* in_sizes, int n_in,
                              void* d_out, int out_size, void* d_ws, size_t ws_size,
                              hipStream_t stream)
{
    const float* x  = (const float*)d_in[0];
    const float* W1 = (const float*)d_in[1];
    const float* b1 = (const float*)d_in[2];
    const float* W2 = (const float*)d_in[3];
    const float* b2 = (const float*)d_in[4];
    float* out = (float*)d_out;
    snn_fused<<<BATCH / 256, 256, 0, stream>>>(x, W1, b1, W2, b2, out);
}